// Round 5
// baseline (171.666 us; speedup 1.0000x reference)
//
#include <hip/hip_runtime.h>

// y = q_tok(x) @ q_grp(W)^T + bias, factored exactly:
//   q(x) = g_x * s_x[m], q(W) = g_w * s_w[n,grp] (grp=128 along K)
//   y[m,n] = s_x[m] * sum_grp s_w[n,grp] * (sum_{k in grp} g_x g_w)
// R10: gemm = 64x64 tile, 4-slot LDS rotation with STATIC slot indices
// (manual unroll-by-4), prefetch depth 2 (vmcnt(4): two tiles in flight),
// ONE barrier per iter (depth-2 makes the read-release barrier redundant),
// XCD-contiguous block remap for A-panel L2 residency. Swizzle (8-row
// period, 0 conflicts, verified R9) kept. Quant w-role reverted to R8.

#define M_TOK 2048
#define N_OUT 4096
#define K_IN  4096
#define KB    2048    // packed fp4 bytes per K row (K_IN/2)
#define XBLK  2048    // x-role: one block per token row
#define WBLK  8192    // w-role: 2048 floats (16 groups) per block

typedef __attribute__((ext_vector_type(4))) int   int4v;
typedef __attribute__((ext_vector_type(8))) int   int8v;
typedef __attribute__((ext_vector_type(4))) float floatx4;

// fp4-e2m1 nibble via scale-premultiplied decision thresholds
// T = {.25,.75,1.25,1.75,2.5,3.5,5}*scale; codes 0..7 = {0,.5,1,1.5,2,3,4,6}
__device__ __forceinline__ unsigned int q_nib(
    float v, float t0, float t1, float t2, float t3, float t4, float t5, float t6)
{
    float a = fabsf(v);
    unsigned int m =
        a < t0 ? 0u : a < t1 ? 1u : a < t2 ? 2u : a < t3 ? 3u :
        a < t4 ? 4u : a < t5 ? 5u : a < t6 ? 6u : 7u;
    return m | ((__float_as_uint(v) >> 28) & 0x8u);
}

#define MK_THR(scale) \
    const float t0 = 0.25f * (scale), t1 = 0.75f * (scale), \
                t2 = 1.25f * (scale), t3 = 1.75f * (scale), \
                t4 = 2.5f  * (scale), t5 = 3.5f  * (scale), \
                t6 = 5.0f  * (scale);

// ---------- fused quant: blocks [0,XBLK) per-token x, rest per-group w ----------
__global__ __launch_bounds__(256) void quant_fused_kernel(
    const float* __restrict__ x, const float* __restrict__ w,
    unsigned char* __restrict__ xq, float* __restrict__ sx,
    unsigned char* __restrict__ wq, float* __restrict__ swt)
{
    const int t = threadIdx.x;
    const int lane = t & 63, wid = t >> 6;

    if (blockIdx.x < XBLK) {
        // ---- per-token row of 4096: clamp [-3,3], scale = absmax/6 ----
        // coalesced: phase i loads float4 at i*1024 + t*4 (16B/lane contiguous)
        const int row = blockIdx.x;
        const float* xr = x + (size_t)row * K_IN;
        float4 v[4];
        float amax = 0.0f;
        #pragma unroll
        for (int i = 0; i < 4; i++) {
            float4 a = *(const float4*)(xr + i * 1024 + t * 4);
            a.x = fminf(fmaxf(a.x, -3.0f), 3.0f);
            a.y = fminf(fmaxf(a.y, -3.0f), 3.0f);
            a.z = fminf(fmaxf(a.z, -3.0f), 3.0f);
            a.w = fminf(fmaxf(a.w, -3.0f), 3.0f);
            v[i] = a;
            amax = fmaxf(amax, fmaxf(fmaxf(fabsf(a.x), fabsf(a.y)),
                                     fmaxf(fabsf(a.z), fabsf(a.w))));
        }
        #pragma unroll
        for (int off = 32; off; off >>= 1)
            amax = fmaxf(amax, __shfl_xor(amax, off));
        __shared__ float smax[4];
        if (lane == 0) smax[wid] = amax;
        __syncthreads();
        amax = fmaxf(fmaxf(smax[0], smax[1]), fmaxf(smax[2], smax[3]));

        const float scale = amax / 6.0f;
        if (t == 0) sx[row] = scale;
        MK_THR(scale);
        unsigned char* xo = xq + (size_t)row * KB;
        #pragma unroll
        for (int i = 0; i < 4; i++) {
            unsigned int u = q_nib(v[i].x, t0,t1,t2,t3,t4,t5,t6)
                           | (q_nib(v[i].y, t0,t1,t2,t3,t4,t5,t6) << 4)
                           | (q_nib(v[i].z, t0,t1,t2,t3,t4,t5,t6) << 8)
                           | (q_nib(v[i].w, t0,t1,t2,t3,t4,t5,t6) << 12);
            *(unsigned short*)(xo + i * 512 + t * 2) = (unsigned short)u;
        }
    } else {
        // ---- per-group w: block = 2048 floats = 16 groups; 16 lanes/group,
        //      8 consecutive elements per lane -> one packed uint ----
        const int b = blockIdx.x - XBLK;
        const float* base = w + (size_t)b * 2048 + t * 8;
        float4 v0 = *(const float4*)base;
        float4 v1 = *(const float4*)(base + 4);
        float vals[8] = {v0.x, v0.y, v0.z, v0.w, v1.x, v1.y, v1.z, v1.w};
        float amax = 0.0f;
        #pragma unroll
        for (int j = 0; j < 8; j++) amax = fmaxf(amax, fabsf(vals[j]));
        #pragma unroll
        for (int off = 4; off; off >>= 1)   // reduce within 16-lane cluster
            amax = fmaxf(amax, __shfl_xor(amax, off));
        amax = fmaxf(amax, __shfl_xor(amax, 8));
        const float scale = amax / 6.0f;
        const int G = b * 16 + (t >> 4);    // flat group id = n*32 + gk
        if ((lane & 15) == 0) swt[(size_t)(G & 31) * N_OUT + (G >> 5)] = scale;
        MK_THR(scale);
        unsigned int u = 0;
        #pragma unroll
        for (int j = 0; j < 8; j++)
            u |= q_nib(vals[j], t0,t1,t2,t3,t4,t5,t6) << (4 * j);
        *(unsigned int*)(wq + (size_t)b * 1024 + t * 4) = u;
    }
}

// ---------- async 16B global->LDS ----------
__device__ __forceinline__ void gld16(const unsigned char* g, unsigned char* l) {
    __builtin_amdgcn_global_load_lds(
        (const __attribute__((address_space(1))) void*)g,
        (__attribute__((address_space(3))) void*)l, 16, 0, 0);
}

// fragment read with the 8-row-period swizzle (verified 0-conflict, R9)
__device__ __forceinline__ int8v frag(const unsigned char* buf, int row, int lq) {
    const int slot = (lq + (row >> 1)) & 3;
    int4v d = *(const int4v*)&buf[row * 64 + slot * 16];
    return (int8v){d[0], d[1], d[2], d[3], 0, 0, 0, 0};
}

// ---------- MX-fp4 GEMM, BK=128 = one quant group per MFMA ----------
// 64x64 tile, 4 waves (2m x 2n), 4-slot LDS rotation (static indices),
// prefetch depth 2, one barrier/iter, setprio around MFMA cluster.
__global__ __launch_bounds__(256, 4) void gemm_mx4_kernel(
    const unsigned char* __restrict__ A, const float* __restrict__ sx,
    const unsigned char* __restrict__ B, const float* __restrict__ swt,
    const float* __restrict__ bias, float* __restrict__ C)
{
    __shared__ __align__(16) unsigned char As[4][64 * 64];   // 16 KB
    __shared__ __align__(16) unsigned char Bs[4][64 * 64];   // 16 KB
    __shared__ __align__(16) float svs[32][64];              // 8 KB

    const int tid = threadIdx.x;
    // XCD-contiguous remap: HW round-robins blockIdx across 8 XCDs, so
    // give XCD k the contiguous tile span [k*256, k*256+256) = 4 m-rows
    // x all 64 n-tiles -> A-panel (512 KB) stays resident in that L2.
    const int nb = ((int)blockIdx.x & 7) * 256 + ((int)blockIdx.x >> 3);
    const int m0 = (nb >> 6) * 64;
    const int n0 = (nb & 63) * 64;
    const int lane = tid & 63;
    const int wid  = tid >> 6;
    const int wm = (wid & 1) * 32;   // wave m-offset: 0/32
    const int wn = (wid >> 1) * 32;  // wave n-offset: 0/32
    const int lr = lane & 15;
    const int lq = lane >> 4;

    floatx4 mast[2][2] = {};

    // staging addresses: swizzle phys-slot = (c + (row>>1)) & 3; inverse on
    // the global source so the LDS dest stays wave-uniform + lane*16.
    const unsigned char* gA;
    const unsigned char* gB;
    int ldst;
    {
        const int row = tid >> 2, ph = tid & 3;
        const int c = (ph - (row >> 1)) & 3;     // logical chunk at phys ph
        gA = A + (size_t)(m0 + row) * KB + c * 16;
        gB = B + (size_t)(n0 + row) * KB + c * 16;
        ldst = tid * 16;
    }

#define STAGE(gg, ss) do {                                     \
        const int koff_ = (gg) * 64;                           \
        gld16(gA + koff_, &As[ss][ldst]);                      \
        gld16(gB + koff_, &Bs[ss][ldst]);                      \
    } while (0)

    // one-time stage of this block's weight scales: swt[g][n0..n0+64)
    // (before STAGE so the compiler's load-use waits don't drain gld16s)
    {
        float4 tmp[2];
        #pragma unroll
        for (int i = 0; i < 2; i++) {
            const int flat = tid + i * 256;      // float4 index, 512 total
            const int g = flat >> 4, c = (flat & 15) << 2;
            tmp[i] = *(const float4*)(swt + (size_t)g * N_OUT + n0 + c);
        }
        #pragma unroll
        for (int i = 0; i < 2; i++) {
            const int flat = tid + i * 256;
            const int g = flat >> 4, c = (flat & 15) << 2;
            *(float4*)&svs[g][c] = tmp[i];
        }
    }
    // prologue: stage k-groups 0,1 into slots 0,1 (4 gld16 in flight)
    STAGE(0, 0);
    STAGE(1, 1);
    asm volatile("s_waitcnt lgkmcnt(0)" ::: "memory");  // svs ds_writes done

    const floatx4 zero = {0.0f, 0.0f, 0.0f, 0.0f};

    // Per-iter: [stage g+2] -> vmcnt -> barrier -> ds_reads -> lgkm(0)
    // -> MFMA. One barrier suffices: stage at iter g overwrites the slot
    // last read at iter g-2, and passing B1(g) transitively implies all
    // waves drained (lgkmcnt 0) their iter g-1 reads.
#define BODY(G, S, STG, VMSTR) do {                                          \
        if (STG) STAGE((G) + 2, ((S) + 2) & 3);                              \
        asm volatile("s_waitcnt " VMSTR ::: "memory");                       \
        __builtin_amdgcn_s_barrier();                                        \
        __builtin_amdgcn_sched_barrier(0);                                   \
        float sv[2]; int8v af[2], bf[2];                                     \
        _Pragma("unroll")                                                    \
        for (int ni = 0; ni < 2; ni++) sv[ni] = svs[G][wn + ni * 16 + lr];   \
        _Pragma("unroll")                                                    \
        for (int mi = 0; mi < 2; mi++) af[mi] = frag(As[S], wm + mi * 16 + lr, lq); \
        _Pragma("unroll")                                                    \
        for (int ni = 0; ni < 2; ni++) bf[ni] = frag(Bs[S], wn + ni * 16 + lr, lq); \
        asm volatile("s_waitcnt lgkmcnt(0)" ::: "memory");                   \
        __builtin_amdgcn_sched_barrier(0);   /* rule #18 */                  \
        __builtin_amdgcn_s_setprio(1);                                       \
        _Pragma("unroll")                                                    \
        for (int mi = 0; mi < 2; mi++)                                       \
        _Pragma("unroll")                                                    \
        for (int ni = 0; ni < 2; ni++) {                                     \
            floatx4 tacc = __builtin_amdgcn_mfma_scale_f32_16x16x128_f8f6f4( \
                af[mi], bf[ni], zero, 4, 4,                                  \
                0, 0x7F7F7F7F, 0, 0x7F7F7F7F);                               \
            mast[mi][ni] += sv[ni] * tacc;                                   \
        }                                                                    \
        __builtin_amdgcn_s_setprio(0);                                       \
    } while (0)

    #pragma unroll 1
    for (int g = 0; g < 28; g += 4) {
        BODY(g + 0, 0, 1, "vmcnt(4)");
        BODY(g + 1, 1, 1, "vmcnt(4)");
        BODY(g + 2, 2, 1, "vmcnt(4)");
        BODY(g + 3, 3, 1, "vmcnt(4)");
    }
    BODY(28, 0, 1, "vmcnt(4)");
    BODY(29, 1, 1, "vmcnt(4)");
    BODY(30, 2, 0, "vmcnt(2)");
    BODY(31, 3, 0, "vmcnt(0)");
#undef BODY
#undef STAGE

    // epilogue: C/D layout col=lane&15, row=(lane>>4)*4+reg [m89/m91]
    #pragma unroll
    for (int mi = 0; mi < 2; mi++) {
        const int rbase = m0 + wm + mi * 16 + lq * 4;
        #pragma unroll
        for (int ni = 0; ni < 2; ni++) {
            const int cc = n0 + wn + ni * 16 + lr;
            const float bb = bias[cc];
            #pragma unroll
            for (int r = 0; r < 4; r++)
                C[(size_t)(rbase + r) * N_OUT + cc] =
                    sx[rbase + r] * mast[mi][ni][r] + bb;
        }
    }
}

extern "C" void kernel_launch(void* const* d_in, const int* in_sizes, int n_in,
                              void* d_out, int out_size, void* d_ws, size_t ws_size,
                              hipStream_t stream) {
    const float* x    = (const float*)d_in[0];
    const float* w    = (const float*)d_in[1];
    const float* bias = (const float*)d_in[2];
    float* out = (float*)d_out;

    unsigned char* xq = (unsigned char*)d_ws;                       // 4 MB
    unsigned char* wq = xq + (size_t)M_TOK * KB;                    // 8 MB
    float* swt = (float*)(wq + (size_t)N_OUT * KB);                 // 512 KB, [32][4096]
    float* sx  = swt + (size_t)(K_IN / 128) * N_OUT;                // 8 KB

    quant_fused_kernel<<<XBLK + WBLK, 256, 0, stream>>>(x, w, xq, sx, wq, swt);
    gemm_mx4_kernel<<<2048, 256, 0, stream>>>(
        xq, sx, wq, swt, bias, out);
}

// Round 6
// 155.729 us; speedup vs baseline: 1.1023x; 1.1023x over previous
//
#include <hip/hip_runtime.h>

// y = q_tok(x) @ q_grp(W)^T + bias, factored exactly:
//   q(x) = g_x * s_x[m], q(W) = g_w * s_w[n,grp] (grp=128 along K)
//   y[m,n] = s_x[m] * sum_grp s_w[n,grp] * (sum_{k in grp} g_x g_w)
// R11: gemm retiled 128x128, wave tile 64x64 -> 8 ds_read_b128 feed 16
// MFMAs (LDS bytes/MFMA halved vs R9/R10 -- LDS port is the serialized
// resource). Structure = R8's proven loop: 2-slot double buffer, static
// g&1 index, STAGE(g+1)->vmcnt(4)->barrier->reads->lgkm(0)->barrier->
// setprio MFMA. R9's 0-conflict 8-row-period swizzle kept (same 64 B row
// stride). XCD remap REVERTED (R10: FETCH 3x, L2 locality destroyed).

#define M_TOK 2048
#define N_OUT 4096
#define K_IN  4096
#define KB    2048    // packed fp4 bytes per K row (K_IN/2)
#define XBLK  2048    // x-role: one block per token row
#define WBLK  8192    // w-role: 2048 floats (16 groups) per block

typedef __attribute__((ext_vector_type(4))) int   int4v;
typedef __attribute__((ext_vector_type(8))) int   int8v;
typedef __attribute__((ext_vector_type(4))) float floatx4;

// fp4-e2m1 nibble via scale-premultiplied decision thresholds
// T = {.25,.75,1.25,1.75,2.5,3.5,5}*scale; codes 0..7 = {0,.5,1,1.5,2,3,4,6}
__device__ __forceinline__ unsigned int q_nib(
    float v, float t0, float t1, float t2, float t3, float t4, float t5, float t6)
{
    float a = fabsf(v);
    unsigned int m =
        a < t0 ? 0u : a < t1 ? 1u : a < t2 ? 2u : a < t3 ? 3u :
        a < t4 ? 4u : a < t5 ? 5u : a < t6 ? 6u : 7u;
    return m | ((__float_as_uint(v) >> 28) & 0x8u);
}

#define MK_THR(scale) \
    const float t0 = 0.25f * (scale), t1 = 0.75f * (scale), \
                t2 = 1.25f * (scale), t3 = 1.75f * (scale), \
                t4 = 2.5f  * (scale), t5 = 3.5f  * (scale), \
                t6 = 5.0f  * (scale);

// ---------- fused quant: blocks [0,XBLK) per-token x, rest per-group w ----------
__global__ __launch_bounds__(256) void quant_fused_kernel(
    const float* __restrict__ x, const float* __restrict__ w,
    unsigned char* __restrict__ xq, float* __restrict__ sx,
    unsigned char* __restrict__ wq, float* __restrict__ swt)
{
    const int t = threadIdx.x;
    const int lane = t & 63, wid = t >> 6;

    if (blockIdx.x < XBLK) {
        // ---- per-token row of 4096: clamp [-3,3], scale = absmax/6 ----
        // coalesced: phase i loads float4 at i*1024 + t*4 (16B/lane contiguous)
        const int row = blockIdx.x;
        const float* xr = x + (size_t)row * K_IN;
        float4 v[4];
        float amax = 0.0f;
        #pragma unroll
        for (int i = 0; i < 4; i++) {
            float4 a = *(const float4*)(xr + i * 1024 + t * 4);
            a.x = fminf(fmaxf(a.x, -3.0f), 3.0f);
            a.y = fminf(fmaxf(a.y, -3.0f), 3.0f);
            a.z = fminf(fmaxf(a.z, -3.0f), 3.0f);
            a.w = fminf(fmaxf(a.w, -3.0f), 3.0f);
            v[i] = a;
            amax = fmaxf(amax, fmaxf(fmaxf(fabsf(a.x), fabsf(a.y)),
                                     fmaxf(fabsf(a.z), fabsf(a.w))));
        }
        #pragma unroll
        for (int off = 32; off; off >>= 1)
            amax = fmaxf(amax, __shfl_xor(amax, off));
        __shared__ float smax[4];
        if (lane == 0) smax[wid] = amax;
        __syncthreads();
        amax = fmaxf(fmaxf(smax[0], smax[1]), fmaxf(smax[2], smax[3]));

        const float scale = amax / 6.0f;
        if (t == 0) sx[row] = scale;
        MK_THR(scale);
        unsigned char* xo = xq + (size_t)row * KB;
        #pragma unroll
        for (int i = 0; i < 4; i++) {
            unsigned int u = q_nib(v[i].x, t0,t1,t2,t3,t4,t5,t6)
                           | (q_nib(v[i].y, t0,t1,t2,t3,t4,t5,t6) << 4)
                           | (q_nib(v[i].z, t0,t1,t2,t3,t4,t5,t6) << 8)
                           | (q_nib(v[i].w, t0,t1,t2,t3,t4,t5,t6) << 12);
            *(unsigned short*)(xo + i * 512 + t * 2) = (unsigned short)u;
        }
    } else {
        // ---- per-group w: block = 2048 floats = 16 groups; 16 lanes/group,
        //      8 consecutive elements per lane -> one packed uint ----
        const int b = blockIdx.x - XBLK;
        const float* base = w + (size_t)b * 2048 + t * 8;
        float4 v0 = *(const float4*)base;
        float4 v1 = *(const float4*)(base + 4);
        float vals[8] = {v0.x, v0.y, v0.z, v0.w, v1.x, v1.y, v1.z, v1.w};
        float amax = 0.0f;
        #pragma unroll
        for (int j = 0; j < 8; j++) amax = fmaxf(amax, fabsf(vals[j]));
        #pragma unroll
        for (int off = 4; off; off >>= 1)   // reduce within 16-lane cluster
            amax = fmaxf(amax, __shfl_xor(amax, off));
        amax = fmaxf(amax, __shfl_xor(amax, 8));
        const float scale = amax / 6.0f;
        const int G = b * 16 + (t >> 4);    // flat group id = n*32 + gk
        if ((lane & 15) == 0) swt[(size_t)(G & 31) * N_OUT + (G >> 5)] = scale;
        MK_THR(scale);
        unsigned int u = 0;
        #pragma unroll
        for (int j = 0; j < 8; j++)
            u |= q_nib(vals[j], t0,t1,t2,t3,t4,t5,t6) << (4 * j);
        *(unsigned int*)(wq + (size_t)b * 1024 + t * 4) = u;
    }
}

// ---------- async 16B global->LDS ----------
__device__ __forceinline__ void gld16(const unsigned char* g, unsigned char* l) {
    __builtin_amdgcn_global_load_lds(
        (const __attribute__((address_space(1))) void*)g,
        (__attribute__((address_space(3))) void*)l, 16, 0, 0);
}

// fragment read with the 8-row-period swizzle (verified 0-conflict, R9;
// same 64 B row stride here)
__device__ __forceinline__ int8v frag(const unsigned char* buf, int row, int lq) {
    const int slot = (lq + (row >> 1)) & 3;
    int4v d = *(const int4v*)&buf[row * 64 + slot * 16];
    return (int8v){d[0], d[1], d[2], d[3], 0, 0, 0, 0};
}

// ---------- MX-fp4 GEMM, BK=128 = one quant group per MFMA ----------
// Tile 128x128, 4 waves (2m x 2n), wave tile 64x64: 8 ds_read_b128 ->
// 16 MFMA per wave-iter. Double-buffered LDS (static g&1), counted
// vmcnt(4), 2 barriers/iter (required at depth-1: next STAGE overwrites
// the buffer just read), setprio around the MFMA cluster.
__global__ __launch_bounds__(256, 2) void gemm_mx4_kernel(
    const unsigned char* __restrict__ A, const float* __restrict__ sx,
    const unsigned char* __restrict__ B, const float* __restrict__ swt,
    const float* __restrict__ bias, float* __restrict__ C)
{
    __shared__ __align__(16) unsigned char As[2][128 * 64];  // 16 KB
    __shared__ __align__(16) unsigned char Bs[2][128 * 64];  // 16 KB
    __shared__ __align__(16) float svs[32][128];             // 16 KB

    const int tid = threadIdx.x;
    const int m0 = blockIdx.y * 128;
    const int n0 = blockIdx.x * 128;
    const int lane = tid & 63;
    const int wid  = tid >> 6;
    const int wm = (wid & 1) * 64;   // wave m-offset: 0/64
    const int wn = (wid >> 1) * 64;  // wave n-offset: 0/64
    const int lr = lane & 15;
    const int lq = lane >> 4;

    floatx4 mast[4][4] = {};

    // staging addresses: swizzle phys-slot = (c + (row>>1)) & 3; inverse on
    // the global source so the LDS dest stays wave-uniform + lane*16.
    // 512 chunks(16B) per operand per slot -> 2/thread each.
    const unsigned char* gA[2];
    const unsigned char* gB[2];
    int ldst[2];
    #pragma unroll
    for (int i = 0; i < 2; i++) {
        const int P = tid + i * 256;
        const int row = P >> 2, ph = P & 3;
        const int c = (ph - (row >> 1)) & 3;     // logical chunk at phys ph
        gA[i] = A + (size_t)(m0 + row) * KB + c * 16;
        gB[i] = B + (size_t)(n0 + row) * KB + c * 16;
        ldst[i] = P * 16;
    }

#define STAGE(gg, ss) do {                                     \
        const int koff_ = (gg) * 64;                           \
        gld16(gA[0] + koff_, &As[ss][ldst[0]]);                \
        gld16(gA[1] + koff_, &As[ss][ldst[1]]);                \
        gld16(gB[0] + koff_, &Bs[ss][ldst[0]]);                \
        gld16(gB[1] + koff_, &Bs[ss][ldst[1]]);                \
    } while (0)

    // one-time stage of this block's weight scales: swt[g][n0..n0+128)
    // (loads issued before STAGE so their waits don't drain gld16s)
    {
        float4 tmp[4];
        #pragma unroll
        for (int i = 0; i < 4; i++) {
            const int flat = tid + i * 256;      // float4 index, 1024 total
            const int g = flat >> 5, c = (flat & 31) << 2;
            tmp[i] = *(const float4*)(swt + (size_t)g * N_OUT + n0 + c);
        }
        #pragma unroll
        for (int i = 0; i < 4; i++) {
            const int flat = tid + i * 256;
            const int g = flat >> 5, c = (flat & 31) << 2;
            *(float4*)&svs[g][c] = tmp[i];
        }
    }
    // prologue: stage k-group 0 into slot 0
    STAGE(0, 0);
    asm volatile("s_waitcnt lgkmcnt(0)" ::: "memory");  // svs ds_writes done

    const floatx4 zero = {0.0f, 0.0f, 0.0f, 0.0f};

    #pragma unroll 2
    for (int g = 0; g < 32; g++) {
        const int cur = g & 1;
        if (g < 31) {
            // issue next tile's 4 loads; wait only for the current 4
            STAGE(g + 1, cur ^ 1);
            asm volatile("s_waitcnt vmcnt(4)" ::: "memory");
        } else {
            asm volatile("s_waitcnt vmcnt(0)" ::: "memory");
        }
        __builtin_amdgcn_s_barrier();            // buf[cur] ready for all
        __builtin_amdgcn_sched_barrier(0);

        float sv[4];
        #pragma unroll
        for (int ni = 0; ni < 4; ni++)
            sv[ni] = svs[g][wn + ni * 16 + lr];

        int8v af[4], bf[4];
        #pragma unroll
        for (int mi = 0; mi < 4; mi++)
            af[mi] = frag(As[cur], wm + mi * 16 + lr, lq);
        #pragma unroll
        for (int ni = 0; ni < 4; ni++)
            bf[ni] = frag(Bs[cur], wn + ni * 16 + lr, lq);

        asm volatile("s_waitcnt lgkmcnt(0)" ::: "memory");
        __builtin_amdgcn_sched_barrier(0);       // rule #18: pin MFMA below
        __builtin_amdgcn_s_barrier();            // buf[cur] free for overwrite

        __builtin_amdgcn_s_setprio(1);
        #pragma unroll
        for (int mi = 0; mi < 4; mi++)
            #pragma unroll
            for (int ni = 0; ni < 4; ni++) {
                floatx4 tacc = __builtin_amdgcn_mfma_scale_f32_16x16x128_f8f6f4(
                    af[mi], bf[ni], zero, 4, 4,          // cbsz=blgp=4 -> fp4
                    0, 0x7F7F7F7F, 0, 0x7F7F7F7F);       // e8m0 scales = 1.0
                mast[mi][ni] += sv[ni] * tacc;
            }
        __builtin_amdgcn_s_setprio(0);
    }
#undef STAGE

    // epilogue: C/D layout col=lane&15, row=(lane>>4)*4+reg [m89/m91]
    #pragma unroll
    for (int mi = 0; mi < 4; mi++) {
        const int rbase = m0 + wm + mi * 16 + lq * 4;
        #pragma unroll
        for (int ni = 0; ni < 4; ni++) {
            const int cc = n0 + wn + ni * 16 + lr;
            const float bb = bias[cc];
            #pragma unroll
            for (int r = 0; r < 4; r++)
                C[(size_t)(rbase + r) * N_OUT + cc] =
                    sx[rbase + r] * mast[mi][ni][r] + bb;
        }
    }
}

extern "C" void kernel_launch(void* const* d_in, const int* in_sizes, int n_in,
                              void* d_out, int out_size, void* d_ws, size_t ws_size,
                              hipStream_t stream) {
    const float* x    = (const float*)d_in[0];
    const float* w    = (const float*)d_in[1];
    const float* bias = (const float*)d_in[2];
    float* out = (float*)d_out;

    unsigned char* xq = (unsigned char*)d_ws;                       // 4 MB
    unsigned char* wq = xq + (size_t)M_TOK * KB;                    // 8 MB
    float* swt = (float*)(wq + (size_t)N_OUT * KB);                 // 512 KB, [32][4096]
    float* sx  = swt + (size_t)(K_IN / 128) * N_OUT;                // 8 KB

    quant_fused_kernel<<<XBLK + WBLK, 256, 0, stream>>>(x, w, xq, sx, wq, swt);
    gemm_mx4_kernel<<<dim3(N_OUT / 128, M_TOK / 128), 256, 0, stream>>>(
        xq, sx, wq, swt, bias, out);
}

// Round 7
// 155.376 us; speedup vs baseline: 1.1048x; 1.0023x over previous
//
#include <hip/hip_runtime.h>

// y = q_tok(x) @ q_grp(W)^T + bias, factored exactly:
//   q(x) = g_x * s_x[m], q(W) = g_w * s_w[n,grp] (grp=128 along K)
//   y[m,n] = s_x[m] * sum_grp s_w[n,grp] * (sum_{k in grp} g_x g_w)
// R12: BK=256 -- two K-groups per barrier period (16 periods, was 32:
// halves barriers/vmcnt waits) + two-phase MFMA: group-0's 16 MFMAs run
// under lgkmcnt(12) while group-1's 12 ds ops are in flight; release
// barrier sits between the phases so group-1 MFMAs overlap other waves'
// staging. All R11-verified primitives kept: static t&1 slot, 0-conflict
// 8-row-period swizzle (sub-tile = R11 layout x2), wave-uniform staging,
// counted vmcnt(8). LDS 80 KB = 2 blocks/CU. Quant unchanged.

#define M_TOK 2048
#define N_OUT 4096
#define K_IN  4096
#define KB    2048    // packed fp4 bytes per K row (K_IN/2)
#define XBLK  2048    // x-role: one block per token row
#define WBLK  8192    // w-role: 2048 floats (16 groups) per block

typedef __attribute__((ext_vector_type(4))) int   int4v;
typedef __attribute__((ext_vector_type(8))) int   int8v;
typedef __attribute__((ext_vector_type(4))) float floatx4;

// fp4-e2m1 nibble via scale-premultiplied decision thresholds
// T = {.25,.75,1.25,1.75,2.5,3.5,5}*scale; codes 0..7 = {0,.5,1,1.5,2,3,4,6}
__device__ __forceinline__ unsigned int q_nib(
    float v, float t0, float t1, float t2, float t3, float t4, float t5, float t6)
{
    float a = fabsf(v);
    unsigned int m =
        a < t0 ? 0u : a < t1 ? 1u : a < t2 ? 2u : a < t3 ? 3u :
        a < t4 ? 4u : a < t5 ? 5u : a < t6 ? 6u : 7u;
    return m | ((__float_as_uint(v) >> 28) & 0x8u);
}

#define MK_THR(scale) \
    const float t0 = 0.25f * (scale), t1 = 0.75f * (scale), \
                t2 = 1.25f * (scale), t3 = 1.75f * (scale), \
                t4 = 2.5f  * (scale), t5 = 3.5f  * (scale), \
                t6 = 5.0f  * (scale);

// ---------- fused quant: blocks [0,XBLK) per-token x, rest per-group w ----------
__global__ __launch_bounds__(256) void quant_fused_kernel(
    const float* __restrict__ x, const float* __restrict__ w,
    unsigned char* __restrict__ xq, float* __restrict__ sx,
    unsigned char* __restrict__ wq, float* __restrict__ swt)
{
    const int t = threadIdx.x;
    const int lane = t & 63, wid = t >> 6;

    if (blockIdx.x < XBLK) {
        // ---- per-token row of 4096: clamp [-3,3], scale = absmax/6 ----
        // coalesced: phase i loads float4 at i*1024 + t*4 (16B/lane contiguous)
        const int row = blockIdx.x;
        const float* xr = x + (size_t)row * K_IN;
        float4 v[4];
        float amax = 0.0f;
        #pragma unroll
        for (int i = 0; i < 4; i++) {
            float4 a = *(const float4*)(xr + i * 1024 + t * 4);
            a.x = fminf(fmaxf(a.x, -3.0f), 3.0f);
            a.y = fminf(fmaxf(a.y, -3.0f), 3.0f);
            a.z = fminf(fmaxf(a.z, -3.0f), 3.0f);
            a.w = fminf(fmaxf(a.w, -3.0f), 3.0f);
            v[i] = a;
            amax = fmaxf(amax, fmaxf(fmaxf(fabsf(a.x), fabsf(a.y)),
                                     fmaxf(fabsf(a.z), fabsf(a.w))));
        }
        #pragma unroll
        for (int off = 32; off; off >>= 1)
            amax = fmaxf(amax, __shfl_xor(amax, off));
        __shared__ float smax[4];
        if (lane == 0) smax[wid] = amax;
        __syncthreads();
        amax = fmaxf(fmaxf(smax[0], smax[1]), fmaxf(smax[2], smax[3]));

        const float scale = amax / 6.0f;
        if (t == 0) sx[row] = scale;
        MK_THR(scale);
        unsigned char* xo = xq + (size_t)row * KB;
        #pragma unroll
        for (int i = 0; i < 4; i++) {
            unsigned int u = q_nib(v[i].x, t0,t1,t2,t3,t4,t5,t6)
                           | (q_nib(v[i].y, t0,t1,t2,t3,t4,t5,t6) << 4)
                           | (q_nib(v[i].z, t0,t1,t2,t3,t4,t5,t6) << 8)
                           | (q_nib(v[i].w, t0,t1,t2,t3,t4,t5,t6) << 12);
            *(unsigned short*)(xo + i * 512 + t * 2) = (unsigned short)u;
        }
    } else {
        // ---- per-group w: block = 2048 floats = 16 groups; 16 lanes/group,
        //      8 consecutive elements per lane -> one packed uint ----
        const int b = blockIdx.x - XBLK;
        const float* base = w + (size_t)b * 2048 + t * 8;
        float4 v0 = *(const float4*)base;
        float4 v1 = *(const float4*)(base + 4);
        float vals[8] = {v0.x, v0.y, v0.z, v0.w, v1.x, v1.y, v1.z, v1.w};
        float amax = 0.0f;
        #pragma unroll
        for (int j = 0; j < 8; j++) amax = fmaxf(amax, fabsf(vals[j]));
        #pragma unroll
        for (int off = 4; off; off >>= 1)   // reduce within 16-lane cluster
            amax = fmaxf(amax, __shfl_xor(amax, off));
        amax = fmaxf(amax, __shfl_xor(amax, 8));
        const float scale = amax / 6.0f;
        const int G = b * 16 + (t >> 4);    // flat group id = n*32 + gk
        if ((lane & 15) == 0) swt[(size_t)(G & 31) * N_OUT + (G >> 5)] = scale;
        MK_THR(scale);
        unsigned int u = 0;
        #pragma unroll
        for (int j = 0; j < 8; j++)
            u |= q_nib(vals[j], t0,t1,t2,t3,t4,t5,t6) << (4 * j);
        *(unsigned int*)(wq + (size_t)b * 1024 + t * 4) = u;
    }
}

// ---------- async 16B global->LDS ----------
__device__ __forceinline__ void gld16(const unsigned char* g, unsigned char* l) {
    __builtin_amdgcn_global_load_lds(
        (const __attribute__((address_space(1))) void*)g,
        (__attribute__((address_space(3))) void*)l, 16, 0, 0);
}

// fragment read with the 8-row-period swizzle (verified 0-conflict, R9/R11)
__device__ __forceinline__ int4v frag4(const unsigned char* buf, int row, int lq) {
    const int slot = (lq + (row >> 1)) & 3;
    return *(const int4v*)&buf[row * 64 + slot * 16];
}
__device__ __forceinline__ int8v ext8(int4v d) {
    return (int8v){d[0], d[1], d[2], d[3], 0, 0, 0, 0};
}

// ---------- MX-fp4 GEMM, BK=256 = two quant groups per barrier period ----------
// Tile 128x128, 4 waves (2m x 2n), wave tile 64x64. Per period: stage
// next super-tile (8 gld16), vmcnt(8), B1, reads g0 (12 ds) | reads g1
// (12 ds), lgkm(12) -> 16 MFMA (g0), lgkm(0) -> B2 (release) -> 16 MFMA
// (g1, overlaps other waves' next staging). Static t&1 slot index.
__global__ __launch_bounds__(256, 2) void gemm_mx4_kernel(
    const unsigned char* __restrict__ A, const float* __restrict__ sx,
    const unsigned char* __restrict__ B, const float* __restrict__ swt,
    const float* __restrict__ bias, float* __restrict__ C)
{
    __shared__ __align__(16) unsigned char As[2][2][128 * 64]; // 32 KB
    __shared__ __align__(16) unsigned char Bs[2][2][128 * 64]; // 32 KB
    __shared__ __align__(16) float svs[32][128];               // 16 KB

    const int tid = threadIdx.x;
    const int m0 = blockIdx.y * 128;
    const int n0 = blockIdx.x * 128;
    const int lane = tid & 63;
    const int wid  = tid >> 6;
    const int wm = (wid & 1) * 64;   // wave m-offset: 0/64
    const int wn = (wid >> 1) * 64;  // wave n-offset: 0/64
    const int lr = lane & 15;
    const int lq = lane >> 4;

    floatx4 mast[4][4] = {};

    // staging addresses: swizzle phys-slot = (c + (row>>1)) & 3; inverse on
    // the global source so the LDS dest stays wave-uniform + lane*16.
    // Per sub-tile (128 rows x 64 B): 512 chunks -> 2/thread per operand.
    const unsigned char* gA[2];
    const unsigned char* gB[2];
    int ldst[2];
    #pragma unroll
    for (int i = 0; i < 2; i++) {
        const int P = tid + i * 256;
        const int row = P >> 2, ph = P & 3;
        const int c = (ph - (row >> 1)) & 3;     // logical chunk at phys ph
        gA[i] = A + (size_t)(m0 + row) * KB + c * 16;
        gB[i] = B + (size_t)(n0 + row) * KB + c * 16;
        ldst[i] = P * 16;
    }

    // STAGE one super-tile (K-groups 2t, 2t+1): 8 gld16
#define STAGE(tt, ss) do {                                     \
        const int koff_ = (tt) * 128;                          \
        _Pragma("unroll")                                      \
        for (int j_ = 0; j_ < 2; j_++) {                       \
            gld16(gA[0] + koff_ + j_ * 64, &As[ss][j_][ldst[0]]); \
            gld16(gA[1] + koff_ + j_ * 64, &As[ss][j_][ldst[1]]); \
            gld16(gB[0] + koff_ + j_ * 64, &Bs[ss][j_][ldst[0]]); \
            gld16(gB[1] + koff_ + j_ * 64, &Bs[ss][j_][ldst[1]]); \
        }                                                      \
    } while (0)

    // one-time stage of this block's weight scales: swt[g][n0..n0+128)
    // (loads issued before STAGE so their waits don't drain gld16s)
    {
        float4 tmp[4];
        #pragma unroll
        for (int i = 0; i < 4; i++) {
            const int flat = tid + i * 256;      // float4 index, 1024 total
            const int g = flat >> 5, c = (flat & 31) << 2;
            tmp[i] = *(const float4*)(swt + (size_t)g * N_OUT + n0 + c);
        }
        #pragma unroll
        for (int i = 0; i < 4; i++) {
            const int flat = tid + i * 256;
            const int g = flat >> 5, c = (flat & 31) << 2;
            *(float4*)&svs[g][c] = tmp[i];
        }
    }
    // prologue: stage super-tile 0 into slot 0
    STAGE(0, 0);
    asm volatile("s_waitcnt lgkmcnt(0)" ::: "memory");  // svs ds_writes done

    const floatx4 zero = {0.0f, 0.0f, 0.0f, 0.0f};

    #pragma unroll 2
    for (int t = 0; t < 16; t++) {
        const int cur = t & 1;
        if (t < 15) {
            STAGE(t + 1, cur ^ 1);               // 8 loads in flight
            asm volatile("s_waitcnt vmcnt(8)" ::: "memory");  // tile t ready
        } else {
            asm volatile("s_waitcnt vmcnt(0)" ::: "memory");
        }
        __builtin_amdgcn_s_barrier();            // B1: slot[cur] published
        __builtin_amdgcn_sched_barrier(0);

        // ---- group 0 reads: sv (4 b32) + 8 b128 = 12 ds ops ----
        float sv0[4];
        #pragma unroll
        for (int ni = 0; ni < 4; ni++)
            sv0[ni] = svs[2 * t][wn + ni * 16 + lr];
        int4v a0[4], b0[4];
        #pragma unroll
        for (int mi = 0; mi < 4; mi++)
            a0[mi] = frag4(As[cur][0], wm + mi * 16 + lr, lq);
        #pragma unroll
        for (int ni = 0; ni < 4; ni++)
            b0[ni] = frag4(Bs[cur][0], wn + ni * 16 + lr, lq);
        __builtin_amdgcn_sched_barrier(0);       // pin g0/g1 issue split

        // ---- group 1 reads: 12 ds ops ----
        float sv1[4];
        #pragma unroll
        for (int ni = 0; ni < 4; ni++)
            sv1[ni] = svs[2 * t + 1][wn + ni * 16 + lr];
        int4v a1[4], b1[4];
        #pragma unroll
        for (int mi = 0; mi < 4; mi++)
            a1[mi] = frag4(As[cur][1], wm + mi * 16 + lr, lq);
        #pragma unroll
        for (int ni = 0; ni < 4; ni++)
            b1[ni] = frag4(Bs[cur][1], wn + ni * 16 + lr, lq);

        // ---- phase A: g0 MFMAs while g1's 12 ds ops are in flight ----
        asm volatile("s_waitcnt lgkmcnt(12)" ::: "memory");
        __builtin_amdgcn_sched_barrier(0);       // rule #18
        __builtin_amdgcn_s_setprio(1);
        #pragma unroll
        for (int mi = 0; mi < 4; mi++)
            #pragma unroll
            for (int ni = 0; ni < 4; ni++) {
                floatx4 tacc = __builtin_amdgcn_mfma_scale_f32_16x16x128_f8f6f4(
                    ext8(a0[mi]), ext8(b0[ni]), zero, 4, 4,   // fp4
                    0, 0x7F7F7F7F, 0, 0x7F7F7F7F);
                mast[mi][ni] += sv0[ni] * tacc;
            }
        __builtin_amdgcn_s_setprio(0);

        // ---- release + phase B: g1 MFMAs overlap next staging ----
        asm volatile("s_waitcnt lgkmcnt(0)" ::: "memory");
        __builtin_amdgcn_sched_barrier(0);       // rule #18
        __builtin_amdgcn_s_barrier();            // B2: slot[cur] free
        __builtin_amdgcn_s_setprio(1);
        #pragma unroll
        for (int mi = 0; mi < 4; mi++)
            #pragma unroll
            for (int ni = 0; ni < 4; ni++) {
                floatx4 tacc = __builtin_amdgcn_mfma_scale_f32_16x16x128_f8f6f4(
                    ext8(a1[mi]), ext8(b1[ni]), zero, 4, 4,
                    0, 0x7F7F7F7F, 0, 0x7F7F7F7F);
                mast[mi][ni] += sv1[ni] * tacc;
            }
        __builtin_amdgcn_s_setprio(0);
    }
#undef STAGE

    // epilogue: C/D layout col=lane&15, row=(lane>>4)*4+reg [m89/m91]
    #pragma unroll
    for (int mi = 0; mi < 4; mi++) {
        const int rbase = m0 + wm + mi * 16 + lq * 4;
        #pragma unroll
        for (int ni = 0; ni < 4; ni++) {
            const int cc = n0 + wn + ni * 16 + lr;
            const float bb = bias[cc];
            #pragma unroll
            for (int r = 0; r < 4; r++)
                C[(size_t)(rbase + r) * N_OUT + cc] =
                    sx[rbase + r] * mast[mi][ni][r] + bb;
        }
    }
}

extern "C" void kernel_launch(void* const* d_in, const int* in_sizes, int n_in,
                              void* d_out, int out_size, void* d_ws, size_t ws_size,
                              hipStream_t stream) {
    const float* x    = (const float*)d_in[0];
    const float* w    = (const float*)d_in[1];
    const float* bias = (const float*)d_in[2];
    float* out = (float*)d_out;

    unsigned char* xq = (unsigned char*)d_ws;                       // 4 MB
    unsigned char* wq = xq + (size_t)M_TOK * KB;                    // 8 MB
    float* swt = (float*)(wq + (size_t)N_OUT * KB);                 // 512 KB, [32][4096]
    float* sx  = swt + (size_t)(K_IN / 128) * N_OUT;                // 8 KB

    quant_fused_kernel<<<XBLK + WBLK, 256, 0, stream>>>(x, w, xq, sx, wq, swt);
    gemm_mx4_kernel<<<dim3(N_OUT / 128, M_TOK / 128), 256, 0, stream>>>(
        xq, sx, wq, swt, bias, out);
}